// Round 1
// baseline (1514.961 us; speedup 1.0000x reference)
//
#include <hip/hip_runtime.h>
#include <math.h>

// ContextualLoss 3D: N=8, C=128, L=16^3=4096.
// Pipeline: mu -> invnorms -> [GEMM pass1 rowmax] -> [pass2 Z] -> [pass3 colmax] -> loss.
// S matrix (8*4096*4096 fp32 = 537MB) is never materialized; cos is recomputed per pass.
// ws usage: 128 + 5*32768 floats ~= 656 KB.

#define NB 8
#define CC 128
#define LL 4096
#define CL (CC * LL)
#define EPSV 1e-5f

// ---------- K1: per-channel mean of y over (n, l) ----------
__global__ void k_mu(const float* __restrict__ y, float* __restrict__ mu) {
    const int c = blockIdx.x;
    const int t = threadIdx.x;
    float s = 0.f;
    for (int n = 0; n < NB; ++n) {
        const float* p = y + (size_t)n * CL + (size_t)c * LL;
        for (int l = t; l < LL; l += 256) s += p[l];
    }
    __shared__ float red[256];
    red[t] = s;
    __syncthreads();
    for (int o = 128; o > 0; o >>= 1) {
        if (t < o) red[t] += red[t + o];
        __syncthreads();
    }
    if (t == 0) mu[c] = red[0] * (1.0f / (float)(NB * LL));
}

// ---------- K2: inverse channel-norm per (n,l): 1/max(||v - mu||, 1e-12) ----------
__global__ void k_invnorm(const float* __restrict__ src, const float* __restrict__ mu,
                          float* __restrict__ invn) {
    const int blk = blockIdx.x;          // NB * (LL/32) = 1024 blocks
    const int n = blk >> 7;
    const int l0 = (blk & 127) << 5;     // 32 l's per block
    const int t = threadIdx.x;
    const int li = t & 31, cg = t >> 5;  // 8 channel-groups x 32 l
    const float* p = src + (size_t)n * CL + l0 + li;
    float s = 0.f;
#pragma unroll
    for (int cc = 0; cc < 16; ++cc) {
        int c = cg * 16 + cc;
        float v = p[(size_t)c * LL] - mu[c];
        s += v * v;
    }
    __shared__ float red[8][32];
    red[cg][li] = s;
    __syncthreads();
    if (t < 32) {
        float tot = 0.f;
#pragma unroll
        for (int g = 0; g < 8; ++g) tot += red[g][t];
        invn[(size_t)n * LL + l0 + t] = 1.0f / fmaxf(sqrtf(tot), 1e-12f);
    }
}

// ---------- staging: load 128(c) x 128(l) tile, center by mu[c], scale by invn[l] ----------
// src layout [n][c][l] is already K-major for the GEMM: LDS tile is lds[k=c][l].
__device__ __forceinline__ void stage_tile(const float* __restrict__ g,   // src + n*CL + l0
                                           const float* __restrict__ mu,
                                           const float* __restrict__ inv, // invn + n*LL + l0
                                           float (*lds)[CC], int t) {
    const int rq = (t & 31) << 2;   // l-quad within tile (constant per lane)
    const int c0 = t >> 5;
    const float4 w = *(const float4*)(inv + rq);
#pragma unroll
    for (int it = 0; it < 16; ++it) {
        int c = c0 + (it << 3);
        float m = mu[c];
        float4 v = *(const float4*)(g + (size_t)c * LL + rq);
        v.x = (v.x - m) * w.x;
        v.y = (v.y - m) * w.y;
        v.z = (v.z - m) * w.z;
        v.w = (v.w - m) * w.w;
        *(float4*)&lds[c][rq] = v;
    }
}

// ---------- 128x128x128 fp32 tile GEMM core; 8x8 per thread, split 4+4 (conflict-free LDS) ----
__device__ __forceinline__ void compute_acc(const float (*As)[CC], const float (*Bs)[CC],
                                            float (&acc)[8][8], int tx, int ty) {
#pragma unroll 2
    for (int k = 0; k < CC; ++k) {
        float4 a0 = *(const float4*)&As[k][ty * 4];
        float4 a1 = *(const float4*)&As[k][64 + ty * 4];
        float4 b0 = *(const float4*)&Bs[k][tx * 4];
        float4 b1 = *(const float4*)&Bs[k][64 + tx * 4];
        float av[8] = {a0.x, a0.y, a0.z, a0.w, a1.x, a1.y, a1.z, a1.w};
        float bv[8] = {b0.x, b0.y, b0.z, b0.w, b1.x, b1.y, b1.z, b1.w};
#pragma unroll
        for (int i = 0; i < 8; ++i)
#pragma unroll
            for (int j = 0; j < 8; ++j)
                acc[i][j] = fmaf(av[i], bv[j], acc[i][j]);
    }
}

__device__ __forceinline__ int row_of(int ty, int i) {
    return (i < 4) ? (ty * 4 + i) : (64 + ty * 4 + (i - 4));
}

// ---------- pass 1: rowmax[n][l] = max_m cos ----------
__global__ __launch_bounds__(256) void k_rowmax(const float* __restrict__ x, const float* __restrict__ y,
                                                const float* __restrict__ mu,
                                                const float* __restrict__ invx, const float* __restrict__ invy,
                                                float* __restrict__ rowmax) {
    __shared__ float As[CC][CC];
    __shared__ float Bs[CC][CC];
    const int n = blockIdx.x >> 5;
    const int lt = blockIdx.x & 31;
    const int t = threadIdx.x;
    const int tx = t & 15, ty = t >> 4;
    stage_tile(x + (size_t)n * CL + lt * CC, mu, invx + (size_t)n * LL + lt * CC, As, t);
    float tmax[8];
#pragma unroll
    for (int i = 0; i < 8; ++i) tmax[i] = -1e30f;
    for (int mt = 0; mt < 32; ++mt) {
        __syncthreads();
        stage_tile(y + (size_t)n * CL + mt * CC, mu, invy + (size_t)n * LL + mt * CC, Bs, t);
        __syncthreads();
        float acc[8][8];
#pragma unroll
        for (int i = 0; i < 8; ++i)
#pragma unroll
            for (int j = 0; j < 8; ++j) acc[i][j] = 0.f;
        compute_acc(As, Bs, acc, tx, ty);
#pragma unroll
        for (int i = 0; i < 8; ++i) {
            float m = acc[i][0];
#pragma unroll
            for (int j = 1; j < 8; ++j) m = fmaxf(m, acc[i][j]);
            tmax[i] = fmaxf(tmax[i], m);
        }
    }
#pragma unroll
    for (int i = 0; i < 8; ++i) {
        float v = tmax[i];
        for (int o = 1; o < 16; o <<= 1) v = fmaxf(v, __shfl_xor(v, o, 64));
        tmax[i] = v;
    }
    if (tx == 0) {
#pragma unroll
        for (int i = 0; i < 8; ++i)
            rowmax[(size_t)n * LL + lt * CC + row_of(ty, i)] = tmax[i];
    }
}

// ---------- pass 2: Zr[n][l] = 1 / sum_m exp(2 - beta*(1-cos)) ----------
__global__ __launch_bounds__(256) void k_z(const float* __restrict__ x, const float* __restrict__ y,
                                           const float* __restrict__ mu,
                                           const float* __restrict__ invx, const float* __restrict__ invy,
                                           const float* __restrict__ rowmax, float* __restrict__ Zr) {
    __shared__ float As[CC][CC];
    __shared__ float Bs[CC][CC];
    const int n = blockIdx.x >> 5;
    const int lt = blockIdx.x & 31;
    const int t = threadIdx.x;
    const int tx = t & 15, ty = t >> 4;
    stage_tile(x + (size_t)n * CL + lt * CC, mu, invx + (size_t)n * LL + lt * CC, As, t);
    float beta[8], zs[8];
#pragma unroll
    for (int i = 0; i < 8; ++i) {
        float rm = rowmax[(size_t)n * LL + lt * CC + row_of(ty, i)];
        beta[i] = 2.0f / (1.0f - rm + EPSV);
        zs[i] = 0.f;
    }
    for (int mt = 0; mt < 32; ++mt) {
        __syncthreads();
        stage_tile(y + (size_t)n * CL + mt * CC, mu, invy + (size_t)n * LL + mt * CC, Bs, t);
        __syncthreads();
        float acc[8][8];
#pragma unroll
        for (int i = 0; i < 8; ++i)
#pragma unroll
            for (int j = 0; j < 8; ++j) acc[i][j] = 0.f;
        compute_acc(As, Bs, acc, tx, ty);
#pragma unroll
        for (int i = 0; i < 8; ++i) {
            float s = 0.f;
#pragma unroll
            for (int j = 0; j < 8; ++j)
                s += __expf(2.0f - beta[i] * (1.0f - acc[i][j]));
            zs[i] += s;
        }
    }
#pragma unroll
    for (int i = 0; i < 8; ++i) {
        float v = zs[i];
        for (int o = 1; o < 16; o <<= 1) v += __shfl_xor(v, o, 64);
        if (tx == 0)
            Zr[(size_t)n * LL + lt * CC + row_of(ty, i)] = 1.0f / v;
    }
}

// ---------- pass 3: colmax[n][m] = max_l exp(2 - beta_l*(1-cos)) * Zr_l ----------
__global__ __launch_bounds__(256) void k_colmax(const float* __restrict__ x, const float* __restrict__ y,
                                                const float* __restrict__ mu,
                                                const float* __restrict__ invx, const float* __restrict__ invy,
                                                const float* __restrict__ rowmax, const float* __restrict__ Zr,
                                                float* __restrict__ colmax) {
    __shared__ float As[CC][CC];  // x row tile (varies over lt)
    __shared__ float Bs[CC][CC];  // y col tile (fixed per block)
    __shared__ unsigned cm[CC];
    const int n = blockIdx.x >> 5;
    const int ct = blockIdx.x & 31;
    const int t = threadIdx.x;
    const int tx = t & 15, ty = t >> 4;
    stage_tile(y + (size_t)n * CL + ct * CC, mu, invy + (size_t)n * LL + ct * CC, Bs, t);
    if (t < CC) cm[t] = 0u;
    float cmax[8];
#pragma unroll
    for (int j = 0; j < 8; ++j) cmax[j] = 0.f;
    for (int lt = 0; lt < 32; ++lt) {
        __syncthreads();
        stage_tile(x + (size_t)n * CL + lt * CC, mu, invx + (size_t)n * LL + lt * CC, As, t);
        __syncthreads();
        float beta[8], zr[8];
#pragma unroll
        for (int i = 0; i < 8; ++i) {
            int r = (size_t)0 + lt * CC + row_of(ty, i);
            float rm = rowmax[(size_t)n * LL + r];
            beta[i] = 2.0f / (1.0f - rm + EPSV);
            zr[i] = Zr[(size_t)n * LL + r];
        }
        float acc[8][8];
#pragma unroll
        for (int i = 0; i < 8; ++i)
#pragma unroll
            for (int j = 0; j < 8; ++j) acc[i][j] = 0.f;
        compute_acc(As, Bs, acc, tx, ty);
#pragma unroll
        for (int i = 0; i < 8; ++i)
#pragma unroll
            for (int j = 0; j < 8; ++j) {
                float v = __expf(2.0f - beta[i] * (1.0f - acc[i][j])) * zr[i];
                cmax[j] = fmaxf(cmax[j], v);
            }
    }
    __syncthreads();
#pragma unroll
    for (int j = 0; j < 8; ++j) {
        int cidx = (j < 4) ? (tx * 4 + j) : (64 + tx * 4 + (j - 4));
        atomicMax(&cm[cidx], __float_as_uint(cmax[j]));  // values >= 0: uint order == float order
    }
    __syncthreads();
    if (t < CC) colmax[(size_t)n * LL + ct * CC + t] = __uint_as_float(cm[t]);
}

// ---------- final: loss = mean_n -log(mean_m colmax + eps) ----------
__global__ void k_loss(const float* __restrict__ colmax, float* __restrict__ out) {
    __shared__ float red[256];
    const int t = threadIdx.x;
    float loss = 0.f;
    for (int n = 0; n < NB; ++n) {
        float s = 0.f;
        for (int m = t; m < LL; m += 256) s += colmax[(size_t)n * LL + m];
        red[t] = s;
        __syncthreads();
        for (int o = 128; o > 0; o >>= 1) {
            if (t < o) red[t] += red[t + o];
            __syncthreads();
        }
        if (t == 0) loss += -logf(red[0] * (1.0f / (float)LL) + EPSV);
        __syncthreads();
    }
    if (t == 0) out[0] = loss * (1.0f / (float)NB);
}

extern "C" void kernel_launch(void* const* d_in, const int* in_sizes, int n_in,
                              void* d_out, int out_size, void* d_ws, size_t ws_size,
                              hipStream_t stream) {
    const float* x = (const float*)d_in[0];
    const float* y = (const float*)d_in[1];
    float* out = (float*)d_out;
    float* ws = (float*)d_ws;
    float* mu     = ws;                 // 128
    float* invx   = ws + 128;           // 32768
    float* invy   = invx + 32768;       // 32768
    float* rowmax = invy + 32768;       // 32768
    float* Zr     = rowmax + 32768;     // 32768
    float* colmax = Zr + 32768;         // 32768  (total ~656 KB)

    k_mu<<<128, 256, 0, stream>>>(y, mu);
    k_invnorm<<<1024, 256, 0, stream>>>(x, mu, invx);
    k_invnorm<<<1024, 256, 0, stream>>>(y, mu, invy);
    k_rowmax<<<256, 256, 0, stream>>>(x, y, mu, invx, invy, rowmax);
    k_z<<<256, 256, 0, stream>>>(x, y, mu, invx, invy, rowmax, Zr);
    k_colmax<<<256, 256, 0, stream>>>(x, y, mu, invx, invy, rowmax, Zr, colmax);
    k_loss<<<1, 256, 0, stream>>>(colmax, out);
}

// Round 2
// 255.297 us; speedup vs baseline: 5.9341x; 5.9341x over previous
//
#include <hip/hip_runtime.h>
#include <math.h>

// ContextualLoss 3D: N=8, C=128, L=4096.
// R2: bf16 MFMA GEMM core (16x16x32), inputs pre-normalized+transposed to [n][l][c] bf16.
// Pipeline: init -> mu -> prep(x) -> prep(y) -> rowmax -> post1(beta) -> Z -> post2(1/Z) -> colmax -> loss.
// ws: xt/yt bf16 (16.8 MB) + mu/beta/Z/rmEnc/cmU (~0.5 MB) = ~17.3 MB.

#define NB 8
#define CC 128
#define LL 4096
#define CL (CC * LL)
#define EPSV 1e-5f
#define LDP 136  // padded bf16 row: 128 + 8 -> balanced (8/bank) ds_read_b128

typedef __bf16 bf16x8 __attribute__((ext_vector_type(8)));
typedef float f32x4 __attribute__((ext_vector_type(4)));

// monotone float<->uint encoding (handles negatives) for atomicMax
__device__ __forceinline__ unsigned encf(float f) {
    unsigned u = __float_as_uint(f);
    return (u & 0x80000000u) ? ~u : (u | 0x80000000u);
}
__device__ __forceinline__ float decf(unsigned u) {
    return __uint_as_float((u & 0x80000000u) ? (u & 0x7FFFFFFFu) : ~u);
}
// f32 -> bf16 bits, round-nearest-even
__device__ __forceinline__ unsigned short f2bf(float f) {
    unsigned u = __float_as_uint(f);
    u += 0x7FFFu + ((u >> 16) & 1u);
    return (unsigned short)(u >> 16);
}

// ---------- init ws accumulators (ws is re-poisoned 0xAA before every launch) ----------
__global__ void k_init(unsigned* __restrict__ rmEnc, float* __restrict__ Z,
                       unsigned* __restrict__ cmU, float* __restrict__ mu) {
    int i = blockIdx.x * 256 + threadIdx.x;  // 32768
    rmEnc[i] = 0x3FFFFFFFu;  // encf(-2.0f): cos >= -1 always
    Z[i] = 0.f;
    cmU[i] = 0u;             // +0.0f; colmax candidates are > 0
    if (i < CC) mu[i] = 0.f;
}

// ---------- per-channel mean of y over (n,l), partials via atomicAdd ----------
__global__ void k_mu(const float* __restrict__ y, float* __restrict__ mu) {
    const int c = blockIdx.x >> 3, s = blockIdx.x & 7;  // 1024 blocks
    const int t = threadIdx.x;
    float sum = 0.f;
    for (int n = 0; n < NB; ++n) {
        const float* p = y + (size_t)n * CL + (size_t)c * LL + (s << 9);
        sum += p[t] + p[t + 256];
    }
    __shared__ float red[256];
    red[t] = sum;
    __syncthreads();
    for (int o = 128; o > 0; o >>= 1) {
        if (t < o) red[t] += red[t + o];
        __syncthreads();
    }
    if (t == 0) atomicAdd(&mu[c], red[0] * (1.0f / (float)(NB * LL)));
}

// ---------- center, L2-normalize over c, emit bf16 transposed [n][l][c] ----------
__global__ __launch_bounds__(256, 2) void k_prep(const float* __restrict__ src,
                                                 const float* __restrict__ mu,
                                                 unsigned short* __restrict__ dst) {
    __shared__ float tf[CC][132];  // [c][l] fp32 tile
    __shared__ float ssq[2][CC];
    __shared__ float invn[CC];
    const int b = blockIdx.x;  // 256: n = b>>5, l-tile = b&31
    const int n = b >> 5, l0 = (b & 31) << 7;
    const int t = threadIdx.x;
    const float* g = src + (size_t)n * CL + l0;
#pragma unroll
    for (int it = 0; it < 16; ++it) {
        int id = (it << 8) + t;            // 4096 float4 chunks
        int c = id >> 5, l4 = (id & 31) << 2;
        *(float4*)&tf[c][l4] = *(const float4*)(g + (size_t)c * LL + l4);
    }
    __syncthreads();
    {   // center + sum-of-squares: thread -> (l, c-half)
        const int l = t & 127, half = t >> 7;
        float ss = 0.f;
#pragma unroll
        for (int cc = 0; cc < 64; ++cc) {
            int c = (half << 6) + cc;
            float v = tf[c][l] - mu[c];
            tf[c][l] = v;
            ss += v * v;
        }
        ssq[half][l] = ss;
    }
    __syncthreads();
    if (t < CC) invn[t] = 1.0f / fmaxf(sqrtf(ssq[0][t] + ssq[1][t]), 1e-12f);
    __syncthreads();
    unsigned short* o = dst + ((size_t)n * LL + l0) * CC;
#pragma unroll
    for (int it = 0; it < 8; ++it) {
        int id = (it << 8) + t;            // 2048 chunks of 8 bf16
        int lr = id >> 4, c8 = (id & 15) << 3;
        float w = invn[lr];
        unsigned short h[8] __attribute__((aligned(16)));
#pragma unroll
        for (int j = 0; j < 8; ++j) h[j] = f2bf(tf[c8 + j][lr] * w);
        *(uint4*)&o[(size_t)lr * CC + c8] = *(uint4*)h;
    }
}

// ---------- stage one 128(l) x 128(c) bf16 tile into padded LDS ----------
__device__ __forceinline__ void stage_bt(const unsigned short* __restrict__ g,
                                         unsigned short (*lds)[LDP], int t) {
#pragma unroll
    for (int it = 0; it < 8; ++it) {
        int id = (it << 8) + t;            // 2048 chunks of 8
        int row = id >> 4, ch = (id & 15) << 3;
        *(uint4*)&lds[row][ch] = *(const uint4*)(g + ((size_t)row << 7) + ch);
    }
}

// ---------- 128x128 (K=128 full) MFMA core: wave w -> 64x64, 4x4 of 16x16x32 ----------
__device__ __forceinline__ void mfma_tile(const unsigned short (*As)[LDP],
                                          const unsigned short (*Bs)[LDP],
                                          f32x4 (&acc)[4][4], int lane, int row0, int col0) {
    const int mr = lane & 15, q = lane >> 4;
#pragma unroll
    for (int k0 = 0; k0 < CC; k0 += 32) {
        bf16x8 a[4], b[4];
#pragma unroll
        for (int i = 0; i < 4; ++i)
            a[i] = *(const bf16x8*)&As[row0 + i * 16 + mr][k0 + q * 8];
#pragma unroll
        for (int j = 0; j < 4; ++j)
            b[j] = *(const bf16x8*)&Bs[col0 + j * 16 + mr][k0 + q * 8];
#pragma unroll
        for (int i = 0; i < 4; ++i)
#pragma unroll
            for (int j = 0; j < 4; ++j)
                acc[i][j] = __builtin_amdgcn_mfma_f32_16x16x32_bf16(a[i], b[j], acc[i][j], 0, 0, 0);
    }
}

// C/D layout (m89/m91-verified): within 16x16 tile, row(M) = quad*4 + reg, col(N) = lane&15.

// ---------- pass 1: rowmax (max over cols) with 2-way m-split, atomicMax ----------
__global__ __launch_bounds__(256, 2) void k_rowmax(const unsigned short* __restrict__ xt,
                                                   const unsigned short* __restrict__ yt,
                                                   unsigned* __restrict__ rmEnc) {
    __shared__ unsigned short As[CC][LDP], Bs[CC][LDP];
    const int b = blockIdx.x;  // 512
    const int n = b >> 6, lt = (b >> 1) & 31, ms = b & 1;
    const int t = threadIdx.x, lane = t & 63, w = t >> 6;
    const int row0 = (w & 1) << 6, col0 = (w >> 1) << 6;
    const int q = lane >> 4;
    stage_bt(xt + ((size_t)n * LL + lt * 128) * CC, As, t);
    float rmax[16];
#pragma unroll
    for (int v = 0; v < 16; ++v) rmax[v] = -1e30f;
    for (int mt = ms * 16; mt < ms * 16 + 16; ++mt) {
        __syncthreads();
        stage_bt(yt + ((size_t)n * LL + mt * 128) * CC, Bs, t);
        __syncthreads();
        f32x4 acc[4][4];
#pragma unroll
        for (int i = 0; i < 4; ++i)
#pragma unroll
            for (int j = 0; j < 4; ++j) acc[i][j] = 0.f;
        mfma_tile(As, Bs, acc, lane, row0, col0);
#pragma unroll
        for (int i = 0; i < 4; ++i)
#pragma unroll
            for (int r = 0; r < 4; ++r) {
                float m = acc[i][0][r];
#pragma unroll
                for (int j = 1; j < 4; ++j) m = fmaxf(m, acc[i][j][r]);
                rmax[i * 4 + r] = fmaxf(rmax[i * 4 + r], m);
            }
    }
#pragma unroll
    for (int v = 0; v < 16; ++v)
        for (int o = 1; o < 16; o <<= 1)
            rmax[v] = fmaxf(rmax[v], __shfl_xor(rmax[v], o, 64));
    if ((lane & 15) == 0) {
#pragma unroll
        for (int v = 0; v < 16; ++v) {
            int row = lt * 128 + row0 + (v >> 2) * 16 + q * 4 + (v & 3);
            atomicMax(&rmEnc[(size_t)n * LL + row], encf(rmax[v]));
        }
    }
}

// ---------- beta[row] = 2/(dmin+eps) ----------
__global__ void k_post1(const unsigned* __restrict__ rmEnc, float* __restrict__ betaArr) {
    int i = blockIdx.x * 256 + threadIdx.x;  // 32768
    float rm = decf(rmEnc[i]);
    betaArr[i] = 2.0f / (1.0f - rm + EPSV);
}

// ---------- pass 2: Z[row] = sum_cols exp(beta*cos + (2-beta)), atomicAdd ----------
__global__ __launch_bounds__(256, 2) void k_z(const unsigned short* __restrict__ xt,
                                              const unsigned short* __restrict__ yt,
                                              const float* __restrict__ betaArr,
                                              float* __restrict__ Z) {
    __shared__ unsigned short As[CC][LDP], Bs[CC][LDP];
    const int b = blockIdx.x;
    const int n = b >> 6, lt = (b >> 1) & 31, ms = b & 1;
    const int t = threadIdx.x, lane = t & 63, w = t >> 6;
    const int row0 = (w & 1) << 6, col0 = (w >> 1) << 6;
    const int q = lane >> 4;
    stage_bt(xt + ((size_t)n * LL + lt * 128) * CC, As, t);
    float beta[16], eb[16], zs[16];
#pragma unroll
    for (int v = 0; v < 16; ++v) {
        int row = lt * 128 + row0 + (v >> 2) * 16 + q * 4 + (v & 3);
        beta[v] = betaArr[(size_t)n * LL + row];
        eb[v] = 2.0f - beta[v];
        zs[v] = 0.f;
    }
    for (int mt = ms * 16; mt < ms * 16 + 16; ++mt) {
        __syncthreads();
        stage_bt(yt + ((size_t)n * LL + mt * 128) * CC, Bs, t);
        __syncthreads();
        f32x4 acc[4][4];
#pragma unroll
        for (int i = 0; i < 4; ++i)
#pragma unroll
            for (int j = 0; j < 4; ++j) acc[i][j] = 0.f;
        mfma_tile(As, Bs, acc, lane, row0, col0);
#pragma unroll
        for (int i = 0; i < 4; ++i)
#pragma unroll
            for (int r = 0; r < 4; ++r) {
                float s = 0.f;
#pragma unroll
                for (int j = 0; j < 4; ++j)
                    s += __expf(fmaf(beta[i * 4 + r], acc[i][j][r], eb[i * 4 + r]));
                zs[i * 4 + r] += s;
            }
    }
#pragma unroll
    for (int v = 0; v < 16; ++v)
        for (int o = 1; o < 16; o <<= 1)
            zs[v] += __shfl_xor(zs[v], o, 64);
    if ((lane & 15) == 0) {
#pragma unroll
        for (int v = 0; v < 16; ++v) {
            int row = lt * 128 + row0 + (v >> 2) * 16 + q * 4 + (v & 3);
            atomicAdd(&Z[(size_t)n * LL + row], zs[v]);
        }
    }
}

// ---------- Zr = 1/Z (in place) ----------
__global__ void k_post2(float* __restrict__ Z) {
    int i = blockIdx.x * 256 + threadIdx.x;
    Z[i] = 1.0f / Z[i];
}

// ---------- pass 3: colmax over rows of exp(..)*Zr, 2-way l-split, atomicMax ----------
__global__ __launch_bounds__(256, 2) void k_colmax(const unsigned short* __restrict__ xt,
                                                   const unsigned short* __restrict__ yt,
                                                   const float* __restrict__ betaArr,
                                                   const float* __restrict__ Zr,
                                                   unsigned* __restrict__ cmU) {
    __shared__ unsigned short As[CC][LDP], Bs[CC][LDP];
    const int b = blockIdx.x;  // 512
    const int n = b >> 6, ct = (b >> 1) & 31, ls = b & 1;
    const int t = threadIdx.x, lane = t & 63, w = t >> 6;
    const int row0 = (w & 1) << 6, col0 = (w >> 1) << 6;
    const int q = lane >> 4;
    stage_bt(yt + ((size_t)n * LL + ct * 128) * CC, Bs, t);  // B = y cols, fixed
    float cmax[4] = {0.f, 0.f, 0.f, 0.f};
    for (int lt = ls * 16; lt < ls * 16 + 16; ++lt) {
        __syncthreads();
        stage_bt(xt + ((size_t)n * LL + lt * 128) * CC, As, t);
        __syncthreads();
        float beta[16], eb[16], zr[16];
#pragma unroll
        for (int v = 0; v < 16; ++v) {
            int row = lt * 128 + row0 + (v >> 2) * 16 + q * 4 + (v & 3);
            beta[v] = betaArr[(size_t)n * LL + row];
            eb[v] = 2.0f - beta[v];
            zr[v] = Zr[(size_t)n * LL + row];
        }
        f32x4 acc[4][4];
#pragma unroll
        for (int i = 0; i < 4; ++i)
#pragma unroll
            for (int j = 0; j < 4; ++j) acc[i][j] = 0.f;
        mfma_tile(As, Bs, acc, lane, row0, col0);
#pragma unroll
        for (int j = 0; j < 4; ++j) {
            float m = cmax[j];
#pragma unroll
            for (int i = 0; i < 4; ++i)
#pragma unroll
                for (int r = 0; r < 4; ++r)
                    m = fmaxf(m, __expf(fmaf(beta[i * 4 + r], acc[i][j][r], eb[i * 4 + r])) * zr[i * 4 + r]);
            cmax[j] = m;
        }
    }
#pragma unroll
    for (int j = 0; j < 4; ++j) {
        cmax[j] = fmaxf(cmax[j], __shfl_xor(cmax[j], 16, 64));
        cmax[j] = fmaxf(cmax[j], __shfl_xor(cmax[j], 32, 64));
    }
    if (lane < 16) {
#pragma unroll
        for (int j = 0; j < 4; ++j) {
            int col = ct * 128 + col0 + j * 16 + lane;
            atomicMax(&cmU[(size_t)n * LL + col], __float_as_uint(cmax[j]));  // all > 0
        }
    }
}

// ---------- final loss ----------
__global__ void k_loss(const float* __restrict__ colmax, float* __restrict__ out) {
    __shared__ float red[256];
    const int t = threadIdx.x;
    float loss = 0.f;
    for (int n = 0; n < NB; ++n) {
        float s = 0.f;
        for (int m = t; m < LL; m += 256) s += colmax[(size_t)n * LL + m];
        red[t] = s;
        __syncthreads();
        for (int o = 128; o > 0; o >>= 1) {
            if (t < o) red[t] += red[t + o];
            __syncthreads();
        }
        if (t == 0) loss += -logf(red[0] * (1.0f / (float)LL) + EPSV);
        __syncthreads();
    }
    if (t == 0) out[0] = loss * (1.0f / (float)NB);
}

extern "C" void kernel_launch(void* const* d_in, const int* in_sizes, int n_in,
                              void* d_out, int out_size, void* d_ws, size_t ws_size,
                              hipStream_t stream) {
    const float* x = (const float*)d_in[0];
    const float* y = (const float*)d_in[1];
    float* out = (float*)d_out;
    char* ws = (char*)d_ws;

    unsigned short* xt = (unsigned short*)ws;                       // 8,388,608 B
    unsigned short* yt = (unsigned short*)(ws + 8388608);           // 8,388,608 B
    float*    mu      = (float*)(ws + 16777216);                    // 512 B
    float*    betaArr = (float*)(ws + 16777216 + 512);              // 131,072 B
    float*    Z       = (float*)(ws + 16777216 + 512 + 131072);     // 131,072 B
    unsigned* rmEnc   = (unsigned*)(ws + 16777216 + 512 + 2 * 131072);
    unsigned* cmU     = (unsigned*)(ws + 16777216 + 512 + 3 * 131072);  // total ~17.3 MB

    k_init<<<128, 256, 0, stream>>>(rmEnc, Z, cmU, mu);
    k_mu<<<1024, 256, 0, stream>>>(y, mu);
    k_prep<<<256, 256, 0, stream>>>(x, mu, xt);
    k_prep<<<256, 256, 0, stream>>>(y, mu, yt);
    k_rowmax<<<512, 256, 0, stream>>>(xt, yt, rmEnc);
    k_post1<<<128, 256, 0, stream>>>(rmEnc, betaArr);
    k_z<<<512, 256, 0, stream>>>(xt, yt, betaArr, Z);
    k_post2<<<128, 256, 0, stream>>>(Z);
    k_colmax<<<512, 256, 0, stream>>>(xt, yt, betaArr, Z, cmU);
    k_loss<<<1, 256, 0, stream>>>((const float*)cmU, out);
}

// Round 3
// 240.693 us; speedup vs baseline: 6.2942x; 1.0607x over previous
//
#include <hip/hip_runtime.h>
#include <math.h>

// ContextualLoss 3D: N=8, C=128, L=4096.
// R3: fixed-operand register-cached fragments (global gather, once per block),
//     streamed operand via global_load_lds(16B) + XOR-granule swizzle (32KB LDS),
//     gamma-trick kills exp in pass3, partial arrays kill all atomics/init.
// Pipeline: mu -> prep -> rowmax -> post1 -> z -> post2 -> colmax -> loss.

#define NB 8
#define CC 128
#define LL 4096
#define CL (CC * LL)
#define EPSV 1e-5f
#define L2E 1.44269504f

typedef __bf16 bf16x8 __attribute__((ext_vector_type(8)));
typedef float f32x4 __attribute__((ext_vector_type(4)));

// f32 -> bf16 bits, round-nearest-even
__device__ __forceinline__ unsigned short f2bf(float f) {
    unsigned u = __float_as_uint(f);
    u += 0x7FFFu + ((u >> 16) & 1u);
    return (unsigned short)(u >> 16);
}

// ---------- per-channel mean of y over (n,l): one block per channel, no atomics ----------
__global__ void k_mu(const float* __restrict__ y, float* __restrict__ mu) {
    const int c = blockIdx.x;  // 128
    const int t = threadIdx.x;
    float s = 0.f;
    for (int n = 0; n < NB; ++n) {
        const float* p = y + (size_t)n * CL + (size_t)c * LL;
        for (int l = t; l < LL; l += 256) s += p[l];
    }
    __shared__ float red[256];
    red[t] = s;
    __syncthreads();
    for (int o = 128; o > 0; o >>= 1) {
        if (t < o) red[t] += red[t + o];
        __syncthreads();
    }
    if (t == 0) mu[c] = red[0] * (1.0f / (float)(NB * LL));
}

// ---------- center, L2-normalize over c, emit bf16 transposed [n][l][c]; x and y in one grid ----------
__global__ __launch_bounds__(256, 2) void k_prep(const float* __restrict__ x, const float* __restrict__ y,
                                                 const float* __restrict__ mu,
                                                 unsigned short* __restrict__ xt, unsigned short* __restrict__ yt) {
    __shared__ float tf[CC][132];  // [c][l] fp32 tile
    __shared__ float ssq[2][CC];
    __shared__ float invn[CC];
    const int b = blockIdx.x;  // 512
    const float* src = (b & 256) ? y : x;
    unsigned short* dst = (b & 256) ? yt : xt;
    const int sub = b & 255;
    const int n = sub >> 5, l0 = (sub & 31) << 7;
    const int t = threadIdx.x;
    const float* g = src + (size_t)n * CL + l0;
#pragma unroll
    for (int it = 0; it < 16; ++it) {
        int id = (it << 8) + t;            // 4096 float4 chunks
        int c = id >> 5, l4 = (id & 31) << 2;
        *(float4*)&tf[c][l4] = *(const float4*)(g + (size_t)c * LL + l4);
    }
    __syncthreads();
    {   // center + sum-of-squares: thread -> (l, c-half)
        const int l = t & 127, half = t >> 7;
        float ss = 0.f;
#pragma unroll
        for (int cc = 0; cc < 64; ++cc) {
            int c = (half << 6) + cc;
            float v = tf[c][l] - mu[c];
            tf[c][l] = v;
            ss += v * v;
        }
        ssq[half][l] = ss;
    }
    __syncthreads();
    if (t < CC) invn[t] = 1.0f / fmaxf(sqrtf(ssq[0][t] + ssq[1][t]), 1e-12f);
    __syncthreads();
    unsigned short* o = dst + ((size_t)n * LL + l0) * CC;
#pragma unroll
    for (int it = 0; it < 8; ++it) {
        int id = (it << 8) + t;            // 2048 chunks of 8 bf16
        int lr = id >> 4, c8 = (id & 15) << 3;
        float w = invn[lr];
        unsigned short h[8] __attribute__((aligned(16)));
#pragma unroll
        for (int j = 0; j < 8; ++j) h[j] = f2bf(tf[c8 + j][lr] * w);
        *(uint4*)&o[(size_t)lr * CC + c8] = *(uint4*)h;
    }
}

// ---------- DMA-stage one 128x128 bf16 tile into unpadded LDS with XOR-granule swizzle ----------
// LDS[r][g] = G[r][g ^ (r&15)]  (granule = 8 bf16 = 16B). Wave w stages rows w*32..w*32+31.
__device__ __forceinline__ void stage_dma(const unsigned short* __restrict__ g,
                                          unsigned short* lds, int t) {
    const int w = t >> 6, ln = t & 63;
#pragma unroll
    for (int c = 0; c < 8; ++c) {
        int rbase = w * 32 + c * 4;
        int row = rbase + (ln >> 4);
        int gg = (ln & 15) ^ (row & 15);
        const unsigned short* gp = g + ((size_t)row << 7) + (gg << 3);
        __builtin_amdgcn_global_load_lds(
            (const __attribute__((address_space(1))) void*)gp,
            (__attribute__((address_space(3))) void*)(lds + (rbase << 7)),
            16, 0, 0);
    }
}

// swizzled fragment read: logical (row r, k-granule kq) -> LDS[r][kq ^ (r&15)]
__device__ __forceinline__ bf16x8 ldsfrag(const unsigned short* lds, int r, int kq) {
    return *(const bf16x8*)&lds[(r << 7) + ((kq ^ (r & 15)) << 3)];
}

// ---------- one-time gather of the fixed tile's fragments from global ----------
// areg[k0i][i] = frag of rows base..base+127 (wave quadrant row0), per verified 16x16x32 A layout.
__device__ __forceinline__ void gather_frags(const unsigned short* __restrict__ g,  // tile base
                                             bf16x8 (&areg)[4][4], int row0, int lane) {
    const int mr = lane & 15, q = lane >> 4;
    const unsigned short* ab = g + ((size_t)(row0 + mr) << 7) + q * 8;
#pragma unroll
    for (int k0i = 0; k0i < 4; ++k0i)
#pragma unroll
        for (int i = 0; i < 4; ++i)
            areg[k0i][i] = *(const bf16x8*)(ab + ((size_t)(i * 16) << 7) + k0i * 32);
}

// MFMA on one streamed LDS tile: fixed frags in areg, streamed frags read swizzled.
__device__ __forceinline__ void mfma_stream(const bf16x8 (&areg)[4][4], const unsigned short* Bs,
                                            f32x4 (&acc)[4][4], int col0, int lane) {
    const int mr = lane & 15, q = lane >> 4;
#pragma unroll
    for (int k0i = 0; k0i < 4; ++k0i) {
        bf16x8 b[4];
#pragma unroll
        for (int j = 0; j < 4; ++j)
            b[j] = ldsfrag(Bs, col0 + j * 16 + mr, 4 * k0i + q);
#pragma unroll
        for (int i = 0; i < 4; ++i)
#pragma unroll
            for (int j = 0; j < 4; ++j)
                acc[i][j] = __builtin_amdgcn_mfma_f32_16x16x32_bf16(areg[k0i][i], b[j], acc[i][j], 0, 0, 0);
    }
}

// C/D layout (verified R2): value acc[i][j][r] -> row = row0+i*16+q*4+r, col = col0+j*16+(lane&15).

// ---------- pass 1: rowmax partials; fixed A = x-tile (regs), streamed B = y-tiles ----------
__global__ __launch_bounds__(256, 2) void k_rowmax(const unsigned short* __restrict__ xt,
                                                   const unsigned short* __restrict__ yt,
                                                   float* __restrict__ rmP) {
    __shared__ unsigned short Bs[CC * CC];
    const int b = blockIdx.x;  // 512
    const int n = b >> 6, lt = (b >> 1) & 31, ms = b & 1;
    const int t = threadIdx.x, lane = t & 63, w = t >> 6;
    const int row0 = (w & 1) << 6, col0 = (w >> 1) << 6;
    const int q = lane >> 4;
    bf16x8 areg[4][4];
    gather_frags(xt + ((size_t)(n * LL + lt * 128) << 7), areg, row0, lane);
    float rmax[16];
#pragma unroll
    for (int v = 0; v < 16; ++v) rmax[v] = -1e30f;
    for (int mt = ms * 16; mt < ms * 16 + 16; ++mt) {
        __syncthreads();
        stage_dma(yt + ((size_t)(n * LL + mt * 128) << 7), Bs, t);
        __syncthreads();
        f32x4 acc[4][4];
#pragma unroll
        for (int i = 0; i < 4; ++i)
#pragma unroll
            for (int j = 0; j < 4; ++j) acc[i][j] = 0.f;
        mfma_stream(areg, Bs, acc, col0, lane);
#pragma unroll
        for (int i = 0; i < 4; ++i)
#pragma unroll
            for (int r = 0; r < 4; ++r) {
                float m = acc[i][0][r];
#pragma unroll
                for (int j = 1; j < 4; ++j) m = fmaxf(m, acc[i][j][r]);
                rmax[i * 4 + r] = fmaxf(rmax[i * 4 + r], m);
            }
    }
#pragma unroll
    for (int v = 0; v < 16; ++v) {
        rmax[v] = fmaxf(rmax[v], __shfl_xor(rmax[v], 1, 64));
        rmax[v] = fmaxf(rmax[v], __shfl_xor(rmax[v], 2, 64));
        rmax[v] = fmaxf(rmax[v], __shfl_xor(rmax[v], 4, 64));
        rmax[v] = fmaxf(rmax[v], __shfl_xor(rmax[v], 8, 64));
    }
    if ((lane & 15) == 0) {
        const int part = ms * 2 + (w >> 1);  // 4 disjoint partials: ms x column-half
#pragma unroll
        for (int v = 0; v < 16; ++v) {
            int row = lt * 128 + row0 + (v >> 2) * 16 + q * 4 + (v & 3);
            rmP[((size_t)part << 15) + n * LL + row] = rmax[v];
        }
    }
}

// ---------- post1: b2 = beta*log2e, e2 = (2-beta)*log2e ----------
__global__ void k_post1(const float* __restrict__ rmP, float* __restrict__ b2A, float* __restrict__ e2A) {
    int i = blockIdx.x * 256 + threadIdx.x;  // 32768
    float rm = fmaxf(fmaxf(rmP[i], rmP[i + (1 << 15)]),
                     fmaxf(rmP[i + (2 << 15)], rmP[i + (3 << 15)]));
    float beta = 2.0f / (1.0f - rm + EPSV);
    b2A[i] = beta * L2E;
    e2A[i] = (2.0f - beta) * L2E;
}

// ---------- pass 2: Z partials = sum_cols 2^(b2*cos + e2) ----------
__global__ __launch_bounds__(256, 2) void k_z(const unsigned short* __restrict__ xt,
                                              const unsigned short* __restrict__ yt,
                                              const float* __restrict__ b2A, const float* __restrict__ e2A,
                                              float* __restrict__ Zp) {
    __shared__ unsigned short Bs[CC * CC];
    const int b = blockIdx.x;  // 512
    const int n = b >> 6, lt = (b >> 1) & 31, ms = b & 1;
    const int t = threadIdx.x, lane = t & 63, w = t >> 6;
    const int row0 = (w & 1) << 6, col0 = (w >> 1) << 6;
    const int q = lane >> 4;
    bf16x8 areg[4][4];
    gather_frags(xt + ((size_t)(n * LL + lt * 128) << 7), areg, row0, lane);
    float b2[16], e2[16], zs[16];
#pragma unroll
    for (int v = 0; v < 16; ++v) {
        int row = lt * 128 + row0 + (v >> 2) * 16 + q * 4 + (v & 3);
        b2[v] = b2A[n * LL + row];
        e2[v] = e2A[n * LL + row];
        zs[v] = 0.f;
    }
    for (int mt = ms * 16; mt < ms * 16 + 16; ++mt) {
        __syncthreads();
        stage_dma(yt + ((size_t)(n * LL + mt * 128) << 7), Bs, t);
        __syncthreads();
        f32x4 acc[4][4];
#pragma unroll
        for (int i = 0; i < 4; ++i)
#pragma unroll
            for (int j = 0; j < 4; ++j) acc[i][j] = 0.f;
        mfma_stream(areg, Bs, acc, col0, lane);
#pragma unroll
        for (int i = 0; i < 4; ++i)
#pragma unroll
            for (int r = 0; r < 4; ++r) {
                int v = i * 4 + r;
                float s = 0.f;
#pragma unroll
                for (int j = 0; j < 4; ++j)
                    s += __builtin_amdgcn_exp2f(fmaf(b2[v], acc[i][j][r], e2[v]));
                zs[v] += s;
            }
    }
#pragma unroll
    for (int v = 0; v < 16; ++v) {
        zs[v] += __shfl_xor(zs[v], 1, 64);
        zs[v] += __shfl_xor(zs[v], 2, 64);
        zs[v] += __shfl_xor(zs[v], 4, 64);
        zs[v] += __shfl_xor(zs[v], 8, 64);
    }
    if ((lane & 15) == 0) {
        const int part = ms * 2 + (w >> 1);
#pragma unroll
        for (int v = 0; v < 16; ++v) {
            int row = lt * 128 + row0 + (v >> 2) * 16 + q * 4 + (v & 3);
            Zp[((size_t)part << 15) + n * LL + row] = zs[v];
        }
    }
}

// ---------- post2: g2 = e2 - log2(Z) ----------
__global__ void k_post2(const float* __restrict__ Zp, const float* __restrict__ e2A,
                        float* __restrict__ g2A) {
    int i = blockIdx.x * 256 + threadIdx.x;
    float Z = (Zp[i] + Zp[i + (1 << 15)]) + (Zp[i + (2 << 15)] + Zp[i + (3 << 15)]);
    g2A[i] = e2A[i] - __builtin_amdgcn_logf(Z);
}

// ---------- pass 3: colmax exponent partials; fixed A = y-cols (regs), streamed B = x-tiles ----
// Output transposed: row = y-col index, col = x-row index -> per-x-row b2/g2 loads are coalesced.
__global__ __launch_bounds__(256, 2) void k_colmax(const unsigned short* __restrict__ xt,
                                                   const unsigned short* __restrict__ yt,
                                                   const float* __restrict__ b2A, const float* __restrict__ g2A,
                                                   float* __restrict__ cmP) {
    __shared__ unsigned short Bs[CC * CC];
    const int b = blockIdx.x;  // 512
    const int n = b >> 6, ct = (b >> 1) & 31, ls = b & 1;
    const int t = threadIdx.x, lane = t & 63, w = t >> 6;
    const int row0 = (w & 1) << 6, col0 = (w >> 1) << 6;
    const int mr = lane & 15, q = lane >> 4;
    bf16x8 areg[4][4];
    gather_frags(yt + ((size_t)(n * LL + ct * 128) << 7), areg, row0, lane);
    float cmax[16];
#pragma unroll
    for (int v = 0; v < 16; ++v) cmax[v] = -1e30f;
    for (int lt = ls * 16; lt < ls * 16 + 16; ++lt) {
        __syncthreads();
        stage_dma(xt + ((size_t)(n * LL + lt * 128) << 7), Bs, t);
        __syncthreads();
        f32x4 acc[4][4];
#pragma unroll
        for (int i = 0; i < 4; ++i)
#pragma unroll
            for (int j = 0; j < 4; ++j) acc[i][j] = 0.f;
        mfma_stream(areg, Bs, acc, col0, lane);
        float b2v[4], g2v[4];
#pragma unroll
        for (int j = 0; j < 4; ++j) {
            int xr = lt * 128 + col0 + j * 16 + mr;
            b2v[j] = b2A[n * LL + xr];
            g2v[j] = g2A[n * LL + xr];
        }
#pragma unroll
        for (int i = 0; i < 4; ++i)
#pragma unroll
            for (int r = 0; r < 4; ++r) {
                int v = i * 4 + r;
                float m = cmax[v];
#pragma unroll
                for (int j = 0; j < 4; ++j)
                    m = fmaxf(m, fmaf(b2v[j], acc[i][j][r], g2v[j]));
                cmax[v] = m;
            }
    }
#pragma unroll
    for (int v = 0; v < 16; ++v) {
        cmax[v] = fmaxf(cmax[v], __shfl_xor(cmax[v], 1, 64));
        cmax[v] = fmaxf(cmax[v], __shfl_xor(cmax[v], 2, 64));
        cmax[v] = fmaxf(cmax[v], __shfl_xor(cmax[v], 4, 64));
        cmax[v] = fmaxf(cmax[v], __shfl_xor(cmax[v], 8, 64));
    }
    if (mr == 0) {
        const int part = ls * 2 + (w >> 1);  // ls x x-row-half
#pragma unroll
        for (int v = 0; v < 16; ++v) {
            int yc = ct * 128 + row0 + (v >> 2) * 16 + q * 4 + (v & 3);
            cmP[((size_t)part << 15) + n * LL + yc] = cmax[v];
        }
    }
}

// ---------- final loss: colmax = 2^max(partial exponents); loss = mean_n -log(mean + eps) ----------
__global__ void k_loss(const float* __restrict__ cmP, float* __restrict__ out) {
    __shared__ float red[1024];
    const int t = threadIdx.x;
    float loss = 0.f;
    for (int n = 0; n < NB; ++n) {
        float s = 0.f;
        for (int m = t; m < LL; m += 1024) {
            size_t idx = (size_t)n * LL + m;
            float e = fmaxf(fmaxf(cmP[idx], cmP[idx + (1 << 15)]),
                            fmaxf(cmP[idx + (2 << 15)], cmP[idx + (3 << 15)]));
            s += __builtin_amdgcn_exp2f(e);
        }
        red[t] = s;
        __syncthreads();
        for (int o = 512; o > 0; o >>= 1) {
            if (t < o) red[t] += red[t + o];
            __syncthreads();
        }
        if (t == 0) loss += -logf(red[0] * (1.0f / (float)LL) + EPSV);
        __syncthreads();
    }
    if (t == 0) out[0] = loss * (1.0f / (float)NB);
}

extern "C" void kernel_launch(void* const* d_in, const int* in_sizes, int n_in,
                              void* d_out, int out_size, void* d_ws, size_t ws_size,
                              hipStream_t stream) {
    const float* x = (const float*)d_in[0];
    const float* y = (const float*)d_in[1];
    float* out = (float*)d_out;
    char* ws = (char*)d_ws;

    unsigned short* xt = (unsigned short*)ws;                    // 8,388,608 B
    unsigned short* yt = (unsigned short*)(ws + 8388608);        // 8,388,608 B
    char* p = ws + 16777216;
    float* mu  = (float*)p;            p += 512;
    float* b2A = (float*)p;            p += 131072;
    float* e2A = (float*)p;            p += 131072;
    float* g2A = (float*)p;            p += 131072;
    float* rmP = (float*)p;            p += 4 * 131072;          // reused as cmP after post1
    float* Zp  = (float*)p;            p += 4 * 131072;          // total ~18.2 MB
    float* cmP = rmP;

    k_mu<<<128, 256, 0, stream>>>(y, mu);
    k_prep<<<512, 256, 0, stream>>>(x, y, mu, xt, yt);
    k_rowmax<<<512, 256, 0, stream>>>(xt, yt, rmP);
    k_post1<<<128, 256, 0, stream>>>(rmP, b2A, e2A);
    k_z<<<512, 256, 0, stream>>>(xt, yt, b2A, e2A, Zp);
    k_post2<<<128, 256, 0, stream>>>(Zp, e2A, g2A);
    k_colmax<<<512, 256, 0, stream>>>(xt, yt, b2A, g2A, cmP);
    k_loss<<<1, 1024, 0, stream>>>(cmP, out);
}